// Round 9
// baseline (60.578 us; speedup 1.0000x reference)
//
#include <hip/hip_runtime.h>
#include <math.h>

typedef _Float16 f16;
typedef _Float16 f16x8 __attribute__((ext_vector_type(8)));
typedef float f32x16 __attribute__((ext_vector_type(16)));

#define TPB 256
#define RB 2                        // 32-row MFMA blocks per wave
#define ROWS_PER_BLOCK (4*RB*32)    // 256 rows per block (4 waves)
#define CC 1024                     // B-points per chunk (32 KB LDS)

static __device__ __forceinline__ unsigned pk(f16 a, f16 b) {
    union { f16 h[2]; unsigned u; } v; v.h[0] = a; v.h[1] = b; return v.u;
}

// Encode each point p as two 16-slot f16 K-vectors such that
//   enc_row(a) . enc_col(b) = |a|^2 + |b|^2 - 2 a.b  (= d^2)  to ~4e-5.
// (verified round 8: absmax 0.0). Also initializes gmin/out every call
// (replaces two memset dispatches; encode precedes mfma/final in-stream).
__global__ __launch_bounds__(TPB) void chamfer_encode(
    const float* __restrict__ P, int NP, const float* __restrict__ T, int NT,
    ushort* __restrict__ Prow, ushort* __restrict__ Pcol,
    ushort* __restrict__ Trow, ushort* __restrict__ Tcol,
    unsigned* __restrict__ gminF, float* __restrict__ out)
{
    const int i = blockIdx.x * TPB + threadIdx.x;
    if (i >= NP + NT) return;
    gminF[i] = 0xFFFFFFFFu;               // gminF and gminB are contiguous
    if (i == 0) *out = 0.f;

    const float* S; ushort *R, *C; int j;
    if (i < NP) { S = P; R = Prow; C = Pcol; j = i; }
    else        { S = T; R = Trow; C = Tcol; j = i - NP; }

    const float x = S[3*j], y = S[3*j+1], z = S[3*j+2];
    const float s2 = x*x + y*y + z*z;
    const float ux = -2.f*x, uy = -2.f*y, uz = -2.f*z;

    const f16 xh = (f16)x,  xl = (f16)(x - (float)xh);
    const f16 yh = (f16)y,  yl = (f16)(y - (float)yh);
    const f16 zh = (f16)z,  zl = (f16)(z - (float)zh);
    const f16 uxh = (f16)ux, uxl = (f16)(ux - (float)uxh);
    const f16 uyh = (f16)uy, uyl = (f16)(uy - (float)uyh);
    const f16 uzh = (f16)uz, uzl = (f16)(uz - (float)uzh);
    const f16 sh = (f16)s2, sl = (f16)(s2 - (float)sh);
    const f16 one = (f16)1.f, zer = (f16)0.f;

    // row (query) enc: [uxh,uxl,uxh, uyh,uyl,uyh, uzh,uzl,uzh, sh,sl, 1,1, 0,0,0]
    uint4 r0 = { pk(uxh,uxl), pk(uxh,uyh), pk(uyl,uyh), pk(uzh,uzl) };
    uint4 r1 = { pk(uzh,sh),  pk(sl,one),  pk(one,zer), pk(zer,zer) };
    // col (target) enc: [xh,xh,xl, yh,yh,yl, zh,zh,zl, 1,1, sh,sl, 0,0,0]
    uint4 c0 = { pk(xh,xh), pk(xl,yh), pk(yh,yl), pk(zh,zh) };
    uint4 c1 = { pk(zl,one), pk(one,sh), pk(sl,zer), pk(zer,zer) };

    *(uint4*)(R + (size_t)j*16)     = r0;
    *(uint4*)(R + (size_t)j*16 + 8) = r1;
    *(uint4*)(C + (size_t)j*16)     = c0;
    *(uint4*)(C + (size_t)j*16 + 8) = c1;
}

// 32x32 tile of d^2 via v_mfma_f32_32x32x16_f16; running row-min in the
// C-layout (verified r8: col=lane&31, row=(reg&3)+8*(reg>>2)+4*(lane>>5)).
// LDS holds fragments in split-k layout [kg][point][8] so frag reads are
// lane-contiguous 16B (r8 had 32B-stride rows -> 8-way conflict, 1.77M cyc).
// Col-blocks processed in pairs: fminf(mr, fminf(d0,d1)) -> v_min3_f32,
// halving min-VALU; zero-acc hoisted so it isn't re-materialized per MFMA
// (r8: MfmaUtil 11%, VALU-bound on 16 fmin + 16 zacc movs per MFMA).
// NO launch_bounds min-waves: caps spilled in r4/r6/r7. LDS(40KB) limits
// occupancy to 4 blocks/CU regardless.
__global__ __launch_bounds__(TPB) void chamfer_mfma(
    const ushort* __restrict__ Prow, int NP, const ushort* __restrict__ Pcol,
    const ushort* __restrict__ Trow, int NT, const ushort* __restrict__ Tcol,
    unsigned* __restrict__ gminF, unsigned* __restrict__ gminB)
{
    const int pass = blockIdx.z;
    const ushort* __restrict__ Aenc = pass ? Trow : Prow;
    const ushort* __restrict__ Benc = pass ? Pcol : Tcol;
    const int NA = pass ? NT : NP;
    const int NB = pass ? NP : NT;
    unsigned* __restrict__ gmin = pass ? gminB : gminF;

    const int rowbase = blockIdx.x * ROWS_PER_BLOCK;
    const int col0 = blockIdx.y * CC;
    if (rowbase >= NA || col0 >= NB) return;

    __shared__ alignas(16) ushort Alds[2 * ROWS_PER_BLOCK * 8];  // 8 KB, [kg][row][8]
    __shared__ alignas(16) ushort Blds[2 * CC * 8];              // 32 KB, [kg][col][8]

    const int tid = threadIdx.x;
    {   // stage A: one encoded row (32 B) per thread, split by k-half
        const int r = min(rowbase + tid, NA - 1);
        const uint4* s = (const uint4*)(Aenc + (size_t)r * 16);
        *(uint4*)(Alds + tid * 8)                       = s[0];   // k0..7
        *(uint4*)(Alds + (ROWS_PER_BLOCK + tid) * 8)    = s[1];   // k8..15
    }
    for (int t = tid; t < CC; t += TPB) {   // stage B chunk, split by k-half
        const int c = min(col0 + t, NB - 1);      // clamp: duplicate cols can't affect min
        const uint4* s = (const uint4*)(Benc + (size_t)c * 16);
        *(uint4*)(Blds + t * 8)          = s[0];
        *(uint4*)(Blds + (CC + t) * 8)   = s[1];
    }
    __syncthreads();

    const int l = tid & 63, w = tid >> 6;
    const int kg = l >> 5;     // k-group: lane's 8 f16 cover k = kg*8..kg*8+7
    const int ln = l & 31;     // row (A) / col (B) within the 32-tile

    f16x8 af[RB];
#pragma unroll
    for (int rb = 0; rb < RB; rb++) {
        const int row = (w * RB + rb) * 32 + ln;
        af[rb] = *(const f16x8*)(Alds + (kg * ROWS_PER_BLOCK + row) * 8);
    }

    const f32x16 kZero = {0,0,0,0,0,0,0,0,0,0,0,0,0,0,0,0};  // hoisted acc-zero
    f32x16 mr[RB];
#pragma unroll
    for (int rb = 0; rb < RB; rb++)
#pragma unroll
        for (int r = 0; r < 16; r++) mr[rb][r] = 3.4e38f;

    const ushort* Bk = Blds + kg * CC * 8;
#pragma unroll 2
    for (int cb = 0; cb < CC / 32; cb += 2) {
        const f16x8 bf0 = *(const f16x8*)(Bk + (cb * 32 + ln) * 8);
        const f16x8 bf1 = *(const f16x8*)(Bk + ((cb + 1) * 32 + ln) * 8);
#pragma unroll
        for (int rb = 0; rb < RB; rb++) {
            f32x16 d0 = __builtin_amdgcn_mfma_f32_32x32x16_f16(af[rb], bf0, kZero, 0, 0, 0);
            f32x16 d1 = __builtin_amdgcn_mfma_f32_32x32x16_f16(af[rb], bf1, kZero, 0, 0, 0);
#pragma unroll
            for (int r = 0; r < 16; r++)
                mr[rb][r] = fminf(mr[rb][r], fminf(d0[r], d1[r]));  // -> v_min3_f32
        }
    }

    // reduce over the 32 cols (lane bits 0-4), then one atomicMin per row
#pragma unroll
    for (int rb = 0; rb < RB; rb++) {
#pragma unroll
        for (int r = 0; r < 16; r++) {
            float v = mr[rb][r];
            v = fminf(v, __shfl_xor(v, 1));
            v = fminf(v, __shfl_xor(v, 2));
            v = fminf(v, __shfl_xor(v, 4));
            v = fminf(v, __shfl_xor(v, 8));
            v = fminf(v, __shfl_xor(v, 16));
            if (ln == 0) {
                const int row = rowbase + (w * RB + rb) * 32 + (r & 3) + 8 * (r >> 2) + 4 * kg;
                if (row < NA)
                    atomicMin(&gmin[row], __float_as_uint(fmaxf(v, 0.f)));
            }
        }
    }
}

// gmin bits -> sqrt -> scaled sum into *out.
__global__ __launch_bounds__(TPB) void chamfer_final(
    const unsigned* __restrict__ gminF, int NP,
    const unsigned* __restrict__ gminB, int NT,
    float scaleF, float scaleB, float* __restrict__ out)
{
    const int gid = blockIdx.x * TPB + threadIdx.x;
    float val = 0.f;
    if (gid < NP) {
        val = sqrtf(fmaxf(__uint_as_float(gminF[gid]), 0.f)) * scaleF;
    } else if (gid < NP + NT) {
        val = sqrtf(fmaxf(__uint_as_float(gminB[gid - NP]), 0.f)) * scaleB;
    }
#pragma unroll
    for (int off = 32; off > 0; off >>= 1) val += __shfl_down(val, off);
    __shared__ float red[TPB / 64];
    const int lane = threadIdx.x & 63;
    const int w = threadIdx.x >> 6;
    if (lane == 0) red[w] = val;
    __syncthreads();
    if (threadIdx.x == 0) {
        float s = 0.f;
#pragma unroll
        for (int i = 0; i < TPB / 64; i++) s += red[i];
        atomicAdd(out, s);
    }
}

extern "C" void kernel_launch(void* const* d_in, const int* in_sizes, int n_in,
                              void* d_out, int out_size, void* d_ws, size_t ws_size,
                              hipStream_t stream) {
    const float* P = (const float*)d_in[0];
    const float* T = (const float*)d_in[1];
    const int NP = in_sizes[0] / 3;
    const int NT = in_sizes[1] / 3;
    float* out = (float*)d_out;

    unsigned* gminF = (unsigned*)d_ws;
    unsigned* gminB = gminF + NP;
    ushort* Prow = (ushort*)(gminB + NT);
    ushort* Pcol = Prow + (size_t)NP * 16;
    ushort* Trow = Pcol + (size_t)NP * 16;
    ushort* Tcol = Trow + (size_t)NT * 16;
    // ws usage: (NP+NT)*4 + (NP+NT)*64 bytes = ~2.3 MB

    const int eblocks = (NP + NT + TPB - 1) / TPB;
    chamfer_encode<<<eblocks, TPB, 0, stream>>>(P, NP, T, NT, Prow, Pcol, Trow, Tcol,
                                                gminF, out);

    const int NAmax = NP > NT ? NP : NT;
    dim3 grid((NAmax + ROWS_PER_BLOCK - 1) / ROWS_PER_BLOCK,
              (NAmax + CC - 1) / CC, 2);
    chamfer_mfma<<<grid, TPB, 0, stream>>>(Prow, NP, Pcol, Trow, NT, Tcol, gminF, gminB);

    const int fblocks = (NP + NT + TPB - 1) / TPB;
    chamfer_final<<<fblocks, TPB, 0, stream>>>(gminF, NP, gminB, NT,
                                               1.0f / (float)NP, 1.0f / (float)NT, out);
}